// Round 3
// baseline (501.971 us; speedup 1.0000x reference)
//
#include <hip/hip_runtime.h>
#include <stdint.h>

#define DIM 128
#define LPAD 136   // padded LDS row stride (bf16 elems); ds_read_b128 pattern conflict-free-ish

static constexpr long long NTOT = 299593LL;

using bf16x8 = __attribute__((ext_vector_type(8))) __bf16;
using f32x4  = __attribute__((ext_vector_type(4))) float;

__device__ __forceinline__ float relu(float x){ return x > 0.f ? x : 0.f; }
__device__ __forceinline__ __bf16 tobf(float x){ return (__bf16)x; }

__device__ __forceinline__ void mfma_acc(f32x4& acc, bf16x8 a, bf16x8 b){
    acc = __builtin_amdgcn_mfma_f32_16x16x32_bf16(a, b, acc, 0, 0, 0);
}

// cooperative: 128x128 bf16 weight (row stride src_stride) -> padded LDS
__device__ __forceinline__ void load_w_lds(const __bf16* __restrict__ wsrc,
                                           __bf16* lds, int src_stride){
    int t = threadIdx.x;
    #pragma unroll
    for (int i = 0; i < 8; ++i){
        int idx = t + i*256;
        int row = idx >> 4, col8 = (idx & 15) << 3;
        *(uint4*)(&lds[row*LPAD + col8]) = *(const uint4*)(wsrc + row*src_stride + col8);
    }
}
// prefetch variant: global -> regs, regs -> LDS (lets loads issue early)
__device__ __forceinline__ void load_w_regs(const __bf16* __restrict__ wsrc,
                                            uint4* wr, int src_stride){
    int t = threadIdx.x;
    #pragma unroll
    for (int i = 0; i < 8; ++i){
        int idx = t + i*256;
        int row = idx >> 4, col8 = (idx & 15) << 3;
        wr[i] = *(const uint4*)(wsrc + row*src_stride + col8);
    }
}
__device__ __forceinline__ void store_w_regs(const uint4* wr, __bf16* lds){
    int t = threadIdx.x;
    #pragma unroll
    for (int i = 0; i < 8; ++i){
        int idx = t + i*256;
        int row = idx >> 4, col8 = (idx & 15) << 3;
        *(uint4*)(&lds[row*LPAD + col8]) = wr[i];
    }
}

// ---- prep: weights fp32->bf16, root ctx = ones ----
__global__ __launch_bounds__(256) void prep_kernel(
    const float* __restrict__ Ws, const float* __restrict__ Wc,
    const float* __restrict__ Wx, const float* __restrict__ Wf,
    __bf16* __restrict__ wts, __bf16* __restrict__ ctx)
{
    int idx = blockIdx.x*256 + threadIdx.x;
    if      (idx < 16384) wts[idx] = tobf(Ws[idx]);
    else if (idx < 32768) wts[idx] = tobf(Wc[idx - 16384]);
    else if (idx < 49152) wts[idx] = tobf(Wx[idx - 32768]);
    else if (idx < 81920) wts[idx] = tobf(Wf[idx - 49152]);
    else if (idx < 82048) ctx[idx - 81920] = tobf(1.0f);       // root context
}

// ---- up level: agg[l] = init[l] + mean_t relu(Wc . mean_s relu(Ws . agg[l+1] + bs) + bc)
template<bool LEAF>
__global__ __launch_bounds__(256, 3) void up_kernel(
    const __bf16* __restrict__ wts,     // Ws @0, Wc @16384
    const float* __restrict__ init,
    const float* __restrict__ bs, const float* __restrict__ bc,
    __bf16* __restrict__ agg,
    long long child_base, long long parent_base, long long n_par)
{
    __shared__ __bf16 lds_w[128*LPAD];
    __shared__ __bf16 lds_sib[32*LPAD];

    const int t = threadIdx.x;
    const int w = t >> 6, lane = t & 63, quad = lane >> 4, l15 = lane & 15;

    const long long n_child = n_par * 8;
    const long long rowbase = (long long)blockIdx.x*128 + w*32;

    // --- prefetch phase: issue ALL global loads up front ---
    bf16x8 af[2][4];
    float4 v[2][4][2];
    #pragma unroll
    for (int tt = 0; tt < 2; ++tt){
        long long r = rowbase + tt*16 + l15;
        if (r >= n_child) r = n_child - 1;
        const long long base = (child_base + r)*DIM;
        #pragma unroll
        for (int ks = 0; ks < 4; ++ks){
            if (LEAF){
                const float* p = init + base + ks*32 + quad*8;
                v[tt][ks][0] = *(const float4*)p;
                v[tt][ks][1] = *(const float4*)(p + 4);
            } else {
                af[tt][ks] = *(const bf16x8*)(agg + base + ks*32 + quad*8);
            }
        }
    }
    float pinit[2][8];
    const long long p0 = (long long)blockIdx.x*16 + w*8 + quad*2;
    if (w < 2){
        long long q0 = p0     < n_par ? p0     : n_par - 1;
        long long q1 = p0 + 1 < n_par ? p0 + 1 : n_par - 1;
        #pragma unroll
        for (int nt = 0; nt < 8; ++nt){
            int col = nt*16 + l15;
            pinit[0][nt] = init[(parent_base + q0)*DIM + col];
            pinit[1][nt] = init[(parent_base + q1)*DIM + col];
        }
    }
    uint4 wcr[8];
    if (!LEAF) load_w_regs(wts + 16384, wcr, 128);   // Wc prefetch (regs)

    load_w_lds(wts, lds_w, 128);                     // Ws -> LDS

    if (LEAF){
        #pragma unroll
        for (int tt = 0; tt < 2; ++tt){
            long long r = rowbase + tt*16 + l15;
            if (r >= n_child) r = n_child - 1;
            const long long base = (child_base + r)*DIM;
            #pragma unroll
            for (int ks = 0; ks < 4; ++ks){
                bf16x8 a;
                a[0]=tobf(v[tt][ks][0].x); a[1]=tobf(v[tt][ks][0].y);
                a[2]=tobf(v[tt][ks][0].z); a[3]=tobf(v[tt][ks][0].w);
                a[4]=tobf(v[tt][ks][1].x); a[5]=tobf(v[tt][ks][1].y);
                a[6]=tobf(v[tt][ks][1].z); a[7]=tobf(v[tt][ks][1].w);
                af[tt][ks] = a;
                *(uint4*)(agg + base + ks*32 + quad*8) = *(uint4*)&a;   // leaf agg
            }
        }
    }
    __syncthreads();

    // --- stage 1: h = relu(Ws.child + bs), sibling mean ---
    f32x4 acc[2][8];
    #pragma unroll
    for (int tt = 0; tt < 2; ++tt)
        #pragma unroll
        for (int i = 0; i < 8; ++i) acc[tt][i] = f32x4{0.f,0.f,0.f,0.f};
    #pragma unroll
    for (int ks = 0; ks < 4; ++ks){
        #pragma unroll
        for (int nt = 0; nt < 8; ++nt){
            bf16x8 bfrag = *(const bf16x8*)&lds_w[(nt*16 + l15)*LPAD + ks*32 + quad*8];
            mfma_acc(acc[0][nt], af[0][ks], bfrag);
            mfma_acc(acc[1][nt], af[1][ks], bfrag);
        }
    }
    #pragma unroll
    for (int tt = 0; tt < 2; ++tt){
        const int g = w*8 + tt*4 + quad;
        #pragma unroll
        for (int nt = 0; nt < 8; ++nt){
            int col = nt*16 + l15;
            float b = bs[col];
            float s = relu(acc[tt][nt][0]+b) + relu(acc[tt][nt][1]+b)
                    + relu(acc[tt][nt][2]+b) + relu(acc[tt][nt][3]+b);
            lds_sib[g*LPAD + col] = tobf(s * 0.25f);
        }
    }
    __syncthreads();
    if (LEAF) load_w_lds(wts + 16384, lds_w, 128);
    else      store_w_regs(wcr, lds_w);              // Wc already in regs
    __syncthreads();

    // --- stage 2 (2 waves): parent agg ---
    if (w < 2){
        f32x4 a2c[8];
        #pragma unroll
        for (int i = 0; i < 8; ++i) a2c[i] = f32x4{0.f,0.f,0.f,0.f};
        bf16x8 a2[4];
        #pragma unroll
        for (int ks = 0; ks < 4; ++ks)
            a2[ks] = *(const bf16x8*)&lds_sib[(w*16 + l15)*LPAD + ks*32 + quad*8];
        #pragma unroll
        for (int ks = 0; ks < 4; ++ks){
            #pragma unroll
            for (int nt = 0; nt < 8; ++nt){
                bf16x8 bfrag = *(const bf16x8*)&lds_w[(nt*16 + l15)*LPAD + ks*32 + quad*8];
                mfma_acc(a2c[nt], a2[ks], bfrag);
            }
        }
        #pragma unroll
        for (int nt = 0; nt < 8; ++nt){
            int col = nt*16 + l15;
            float b = bc[col];
            float r01 = 0.5f*(relu(a2c[nt][0]+b) + relu(a2c[nt][1]+b));
            float r23 = 0.5f*(relu(a2c[nt][2]+b) + relu(a2c[nt][3]+b));
            if (p0 < n_par)
                agg[(parent_base + p0)*DIM + col] = tobf(pinit[0][nt] + r01);
            if (p0 + 1 < n_par)
                agg[(parent_base + p0 + 1)*DIM + col] = tobf(pinit[1][nt] + r23);
        }
    }
}

// ---- down level + fused final for the children ----
// ctx[child] = (ctxh[parent] + sum_sibs h - h_self)/4 ; out[child] = Wh.relu(Wf.[ctx,agg]+bf)+bh
template<bool WRITE_CTX>
__global__ __launch_bounds__(256, 2) void down_kernel(
    const __bf16* __restrict__ wts,     // Wx @32768, Wf @49152 (row stride 256)
    const float* __restrict__ bx,
    const __bf16* __restrict__ agg,
    __bf16* __restrict__ ctx,
    const float* __restrict__ bf_,
    const float* __restrict__ Wh, const float* __restrict__ bh,
    float* __restrict__ out,
    long long parent_base, long long child_base, long long n_par)
{
    __shared__ __bf16 lds_w[128*LPAD];
    __shared__ __bf16 lds_tile[128*LPAD];
    __shared__ float lds_ctxh[16*132];

    const int t = threadIdx.x;
    const int w = t >> 6, lane = t & 63, quad = lane >> 4, l15 = lane & 15;
    const long long n_child = n_par*8;
    const long long rowbase = (long long)blockIdx.x*128 + w*32;

    // --- prefetch: child agg frags, parent ctx (wave0), both Wf halves ---
    bf16x8 a[2][4];
    #pragma unroll
    for (int tt = 0; tt < 2; ++tt){
        long long r = rowbase + tt*16 + l15;
        if (r >= n_child) r = n_child - 1;
        #pragma unroll
        for (int ks = 0; ks < 4; ++ks)
            a[tt][ks] = *(const bf16x8*)(agg + (child_base + r)*DIM + ks*32 + quad*8);
    }
    bf16x8 pc[4];
    if (w == 0){
        long long p = (long long)blockIdx.x*16 + l15;
        if (p >= n_par) p = n_par - 1;
        #pragma unroll
        for (int ks = 0; ks < 4; ++ks)
            pc[ks] = *(const bf16x8*)(ctx + (parent_base + p)*DIM + ks*32 + quad*8);
    }
    uint4 wfc[8], wfa[8];
    load_w_regs(wts + 49152,       wfc, 256);   // Wf[:,0:128]   (ctx half)
    load_w_regs(wts + 49152 + 128, wfa, 256);   // Wf[:,128:256] (agg half)
    load_w_lds(wts + 32768, lds_w, 128);        // Wx -> LDS
    __syncthreads();

    // --- wave0: ctx_h for the block's 16 parents ---
    if (w == 0){
        f32x4 cacc[8];
        #pragma unroll
        for (int i = 0; i < 8; ++i) cacc[i] = f32x4{0.f,0.f,0.f,0.f};
        #pragma unroll
        for (int ks = 0; ks < 4; ++ks){
            #pragma unroll
            for (int nt = 0; nt < 8; ++nt){
                bf16x8 bfrag = *(const bf16x8*)&lds_w[(nt*16 + l15)*LPAD + ks*32 + quad*8];
                mfma_acc(cacc[nt], pc[ks], bfrag);
            }
        }
        #pragma unroll
        for (int nt = 0; nt < 8; ++nt){
            int col = nt*16 + l15;
            float b = bx[col];
            #pragma unroll
            for (int rg = 0; rg < 4; ++rg)
                lds_ctxh[(quad*4 + rg)*132 + col] = relu(cacc[nt][rg] + b);
        }
    }

    // --- main: h = relu(Wx.child_agg + bx) ---
    f32x4 acc[2][8];
    #pragma unroll
    for (int tt = 0; tt < 2; ++tt)
        #pragma unroll
        for (int i = 0; i < 8; ++i) acc[tt][i] = f32x4{0.f,0.f,0.f,0.f};
    #pragma unroll
    for (int ks = 0; ks < 4; ++ks){
        #pragma unroll
        for (int nt = 0; nt < 8; ++nt){
            bf16x8 bfrag = *(const bf16x8*)&lds_w[(nt*16 + l15)*LPAD + ks*32 + quad*8];
            mfma_acc(acc[0][nt], a[0][ks], bfrag);
            mfma_acc(acc[1][nt], a[1][ks], bfrag);
        }
    }
    __syncthreads();   // ctxh ready; all Wx reads done

    // --- epilogue 1: child ctx -> LDS tile (+ global if needed) ---
    #pragma unroll
    for (int tt = 0; tt < 2; ++tt){
        const long long rb = rowbase + tt*16 + quad*4;
        const int lrow = w*32 + tt*16 + quad*4;
        const int p_loc = w*4 + tt*2 + (quad >> 1);
        #pragma unroll
        for (int nt = 0; nt < 8; ++nt){
            int col = nt*16 + l15;
            float b = bx[col];
            float h0 = relu(acc[tt][nt][0]+b), h1 = relu(acc[tt][nt][1]+b);
            float h2 = relu(acc[tt][nt][2]+b), h3 = relu(acc[tt][nt][3]+b);
            float s = h0 + h1 + h2 + h3;
            float ch = lds_ctxh[p_loc*132 + col];
            float c0 = (ch + s - h0)*0.25f, c1 = (ch + s - h1)*0.25f;
            float c2 = (ch + s - h2)*0.25f, c3 = (ch + s - h3)*0.25f;
            lds_tile[(lrow+0)*LPAD + col] = tobf(c0);
            lds_tile[(lrow+1)*LPAD + col] = tobf(c1);
            lds_tile[(lrow+2)*LPAD + col] = tobf(c2);
            lds_tile[(lrow+3)*LPAD + col] = tobf(c3);
            if (WRITE_CTX){
                if (rb   < n_child) ctx[(child_base + rb  )*DIM + col] = tobf(c0);
                if (rb+1 < n_child) ctx[(child_base + rb+1)*DIM + col] = tobf(c1);
                if (rb+2 < n_child) ctx[(child_base + rb+2)*DIM + col] = tobf(c2);
                if (rb+3 < n_child) ctx[(child_base + rb+3)*DIM + col] = tobf(c3);
            }
        }
    }
    store_w_regs(wfc, lds_w);          // Wf ctx-half (regs -> LDS)
    __syncthreads();                   // tile + Wf_ctx ready

    // --- fused final: x = relu([ctx,agg].Wf^T + bf) ---
    #pragma unroll
    for (int tt = 0; tt < 2; ++tt)
        #pragma unroll
        for (int i = 0; i < 8; ++i) acc[tt][i] = f32x4{0.f,0.f,0.f,0.f};
    bf16x8 ac[2][4];
    #pragma unroll
    for (int tt = 0; tt < 2; ++tt)
        #pragma unroll
        for (int ks = 0; ks < 4; ++ks)
            ac[tt][ks] = *(const bf16x8*)&lds_tile[(w*32 + tt*16 + l15)*LPAD + ks*32 + quad*8];
    #pragma unroll
    for (int ks = 0; ks < 4; ++ks){
        #pragma unroll
        for (int nt = 0; nt < 8; ++nt){
            bf16x8 bfrag = *(const bf16x8*)&lds_w[(nt*16 + l15)*LPAD + ks*32 + quad*8];
            mfma_acc(acc[0][nt], ac[0][ks], bfrag);
            mfma_acc(acc[1][nt], ac[1][ks], bfrag);
        }
    }
    __syncthreads();                   // Wf_ctx reads done
    store_w_regs(wfa, lds_w);          // Wf agg-half
    __syncthreads();
    #pragma unroll
    for (int ks = 0; ks < 4; ++ks){
        #pragma unroll
        for (int nt = 0; nt < 8; ++nt){
            bf16x8 bfrag = *(const bf16x8*)&lds_w[(nt*16 + l15)*LPAD + ks*32 + quad*8];
            mfma_acc(acc[0][nt], a[0][ks], bfrag);
            mfma_acc(acc[1][nt], a[1][ks], bfrag);
        }
    }
    // --- out = relu(x+bf).Wh + bh ---
    #pragma unroll
    for (int tt = 0; tt < 2; ++tt){
        float q0 = 0.f, q1 = 0.f, q2 = 0.f, q3 = 0.f;
        #pragma unroll
        for (int nt = 0; nt < 8; ++nt){
            int col = nt*16 + l15;
            float b = bf_[col], wh = Wh[col];
            q0 += relu(acc[tt][nt][0]+b)*wh;
            q1 += relu(acc[tt][nt][1]+b)*wh;
            q2 += relu(acc[tt][nt][2]+b)*wh;
            q3 += relu(acc[tt][nt][3]+b)*wh;
        }
        #pragma unroll
        for (int m = 1; m < 16; m <<= 1){
            q0 += __shfl_xor(q0, m);
            q1 += __shfl_xor(q1, m);
            q2 += __shfl_xor(q2, m);
            q3 += __shfl_xor(q3, m);
        }
        if (l15 == 0){
            float bb = bh[0];
            long long r = rowbase + tt*16 + quad*4;
            if (r   < n_child) out[child_base + r  ] = q0 + bb;
            if (r+1 < n_child) out[child_base + r+1] = q1 + bb;
            if (r+2 < n_child) out[child_base + r+2] = q2 + bb;
            if (r+3 < n_child) out[child_base + r+3] = q3 + bb;
        }
    }
}

// ---- root's final output (1 node; ctx = exact ones) ----
__global__ __launch_bounds__(128) void root_final_kernel(
    const float* __restrict__ Wf, const float* __restrict__ bf_,
    const float* __restrict__ Wh, const float* __restrict__ bh,
    const __bf16* __restrict__ agg, float* __restrict__ out)
{
    __shared__ float red[2];
    int j = threadIdx.x;
    float s = bf_[j];
    #pragma unroll 4
    for (int c = 0; c < 128; ++c) s += Wf[j*256 + c];                    // ctx = 1
    #pragma unroll 4
    for (int c = 0; c < 128; ++c) s += Wf[j*256 + 128 + c] * (float)agg[c];
    float x = relu(s) * Wh[j];
    #pragma unroll
    for (int m = 1; m < 64; m <<= 1) x += __shfl_xor(x, m);
    if ((j & 63) == 0) red[j >> 6] = x;
    __syncthreads();
    if (j == 0) out[0] = red[0] + red[1] + bh[0];
}

extern "C" void kernel_launch(void* const* d_in, const int* in_sizes, int n_in,
                              void* d_out, int out_size, void* d_ws, size_t ws_size,
                              hipStream_t stream)
{
    const float* init = (const float*)d_in[0];
    const float* Ws  = (const float*)d_in[1];
    const float* bs  = (const float*)d_in[2];
    const float* Wc  = (const float*)d_in[3];
    const float* bc  = (const float*)d_in[4];
    const float* Wx  = (const float*)d_in[5];
    const float* bx  = (const float*)d_in[6];
    const float* Wf  = (const float*)d_in[7];
    const float* bff = (const float*)d_in[8];
    const float* Wh  = (const float*)d_in[9];
    const float* bh  = (const float*)d_in[10];
    float* out = (float*)d_out;

    __bf16* agg = (__bf16*)d_ws;
    __bf16* ctx = agg + NTOT*DIM;
    __bf16* wts = ctx + NTOT*DIM;

    static const long long SZ[7] = {1,8,64,512,4096,32768,262144};
    static const long long OF[8] = {0,1,9,73,585,4681,37449,299593};

    prep_kernel<<<dim3(321), dim3(256), 0, stream>>>(Ws, Wc, Wx, Wf, wts, ctx);

    for (int l = 5; l >= 0; --l){
        int blocks = (int)((SZ[l]*8 + 127)/128);
        if (l == 5)
            up_kernel<true><<<dim3(blocks), dim3(256), 0, stream>>>(
                wts, init, bs, bc, agg, OF[6], OF[5], SZ[5]);
        else
            up_kernel<false><<<dim3(blocks), dim3(256), 0, stream>>>(
                wts, init, bs, bc, agg, OF[l+1], OF[l], SZ[l]);
    }
    root_final_kernel<<<dim3(1), dim3(128), 0, stream>>>(Wf, bff, Wh, bh, agg, out);

    for (int l = 0; l < 6; ++l){
        int blocks = (int)((SZ[l]*8 + 127)/128);
        if (l == 5)
            down_kernel<false><<<dim3(blocks), dim3(256), 0, stream>>>(
                wts, bx, agg, ctx, bff, Wh, bh, out, OF[5], OF[6], SZ[5]);
        else
            down_kernel<true><<<dim3(blocks), dim3(256), 0, stream>>>(
                wts, bx, agg, ctx, bff, Wh, bh, out, OF[l], OF[l+1], SZ[l]);
    }
}

// Round 4
// 487.127 us; speedup vs baseline: 1.0305x; 1.0305x over previous
//
#include <hip/hip_runtime.h>
#include <stdint.h>

#define DIM 128
#define LPAD 136   // padded LDS row stride (bf16): rows shift 4 banks -> b128 reads ~conflict-free

static constexpr long long NTOT = 299593LL;

using bf16x8 = __attribute__((ext_vector_type(8))) __bf16;
using f32x4  = __attribute__((ext_vector_type(4))) float;

__device__ __forceinline__ float relu(float x){ return x > 0.f ? x : 0.f; }
__device__ __forceinline__ __bf16 tobf(float x){ return (__bf16)x; }

__device__ __forceinline__ void mfma_acc(f32x4& acc, bf16x8 a, bf16x8 b){
    acc = __builtin_amdgcn_mfma_f32_16x16x32_bf16(a, b, acc, 0, 0, 0);
}

// cooperative: 128x128 bf16 weight (row stride src_stride) -> padded LDS
__device__ __forceinline__ void load_w_lds(const __bf16* __restrict__ wsrc,
                                           __bf16* lds, int src_stride){
    int t = threadIdx.x;
    #pragma unroll
    for (int i = 0; i < 8; ++i){
        int idx = t + i*256;
        int row = idx >> 4, col8 = (idx & 15) << 3;
        *(uint4*)(&lds[row*LPAD + col8]) = *(const uint4*)(wsrc + row*src_stride + col8);
    }
}

// ---- prep: weights fp32->bf16, root ctx = ones ----
__global__ __launch_bounds__(256) void prep_kernel(
    const float* __restrict__ Ws, const float* __restrict__ Wc,
    const float* __restrict__ Wx, const float* __restrict__ Wf,
    __bf16* __restrict__ wts, __bf16* __restrict__ ctx)
{
    int idx = blockIdx.x*256 + threadIdx.x;
    if      (idx < 16384) wts[idx] = tobf(Ws[idx]);
    else if (idx < 32768) wts[idx] = tobf(Wc[idx - 16384]);
    else if (idx < 49152) wts[idx] = tobf(Wx[idx - 32768]);
    else if (idx < 81920) wts[idx] = tobf(Wf[idx - 49152]);
    else if (idx < 82048) ctx[idx - 81920] = tobf(1.0f);       // root context
}

// ============================================================================
// up level (tile loop): agg[l] = init[l] + mean_t relu(Wc.mean_s relu(Ws.ch+bs)+bc)
// Weights staged in LDS ONCE; grid-stride loop over 128-child tiles;
// next tile's global loads issue before the barriers (software pipeline).
// ============================================================================
template<bool LEAF>
__global__ __launch_bounds__(256, 2) void up_kernel(
    const __bf16* __restrict__ wts,     // Ws @0, Wc @16384
    const float* __restrict__ init,
    const float* __restrict__ bs, const float* __restrict__ bc,
    __bf16* __restrict__ agg,
    long long child_base, long long parent_base, long long n_par)
{
    __shared__ __bf16 lds_ws[128*LPAD];
    __shared__ __bf16 lds_wc[128*LPAD];
    __shared__ __bf16 lds_sib[32*LPAD];

    const int t = threadIdx.x;
    const int w = t >> 6, lane = t & 63, quad = lane >> 4, l15 = lane & 15;
    const long long n_child = n_par * 8;
    const int ntiles = (int)((n_child + 127) >> 7);
    const int G = gridDim.x;

    bf16x8 af[2][4];
    float4 v[2][4][2];

    int tile = blockIdx.x;
    // prologue: issue tile-0 loads before weight staging
    #pragma unroll
    for (int tt = 0; tt < 2; ++tt){
        long long r = (long long)tile*128 + w*32 + tt*16 + l15;
        if (r >= n_child) r = n_child - 1;
        const long long base = (child_base + r)*DIM;
        #pragma unroll
        for (int ks = 0; ks < 4; ++ks){
            if (LEAF){
                const float* p = init + base + ks*32 + quad*8;
                v[tt][ks][0] = *(const float4*)p;
                v[tt][ks][1] = *(const float4*)(p + 4);
            } else {
                af[tt][ks] = *(const bf16x8*)(agg + base + ks*32 + quad*8);
            }
        }
    }
    load_w_lds(wts,         lds_ws, 128);
    load_w_lds(wts + 16384, lds_wc, 128);
    __syncthreads();

    while (tile < ntiles){
        if (LEAF){          // convert + materialize bf16 leaf agg
            #pragma unroll
            for (int tt = 0; tt < 2; ++tt){
                long long r = (long long)tile*128 + w*32 + tt*16 + l15;
                if (r >= n_child) r = n_child - 1;
                const long long base = (child_base + r)*DIM;
                #pragma unroll
                for (int ks = 0; ks < 4; ++ks){
                    bf16x8 a;
                    a[0]=tobf(v[tt][ks][0].x); a[1]=tobf(v[tt][ks][0].y);
                    a[2]=tobf(v[tt][ks][0].z); a[3]=tobf(v[tt][ks][0].w);
                    a[4]=tobf(v[tt][ks][1].x); a[5]=tobf(v[tt][ks][1].y);
                    a[6]=tobf(v[tt][ks][1].z); a[7]=tobf(v[tt][ks][1].w);
                    af[tt][ks] = a;
                    *(uint4*)(agg + base + ks*32 + quad*8) = *(uint4*)&a;
                }
            }
        }
        // parent init (used in stage 2)
        float pinit[2][8];
        const long long p0 = (long long)tile*16 + w*8 + quad*2;
        if (w < 2){
            long long q0 = p0     < n_par ? p0     : n_par - 1;
            long long q1 = p0 + 1 < n_par ? p0 + 1 : n_par - 1;
            #pragma unroll
            for (int nt = 0; nt < 8; ++nt){
                int col = nt*16 + l15;
                pinit[0][nt] = init[(parent_base + q0)*DIM + col];
                pinit[1][nt] = init[(parent_base + q1)*DIM + col];
            }
        }
        // stage 1: h = relu(Ws.child + bs)
        f32x4 acc[2][8];
        #pragma unroll
        for (int tt = 0; tt < 2; ++tt)
            #pragma unroll
            for (int i = 0; i < 8; ++i) acc[tt][i] = f32x4{0.f,0.f,0.f,0.f};
        #pragma unroll
        for (int ks = 0; ks < 4; ++ks){
            #pragma unroll
            for (int nt = 0; nt < 8; ++nt){
                bf16x8 bfrag = *(const bf16x8*)&lds_ws[(nt*16 + l15)*LPAD + ks*32 + quad*8];
                mfma_acc(acc[0][nt], af[0][ks], bfrag);
                mfma_acc(acc[1][nt], af[1][ks], bfrag);
            }
        }
        // prefetch next tile (flies across the barriers below)
        const int next = tile + G;
        if (next < ntiles){
            #pragma unroll
            for (int tt = 0; tt < 2; ++tt){
                long long r = (long long)next*128 + w*32 + tt*16 + l15;
                if (r >= n_child) r = n_child - 1;
                const long long base = (child_base + r)*DIM;
                #pragma unroll
                for (int ks = 0; ks < 4; ++ks){
                    if (LEAF){
                        const float* p = init + base + ks*32 + quad*8;
                        v[tt][ks][0] = *(const float4*)p;
                        v[tt][ks][1] = *(const float4*)(p + 4);
                    } else {
                        af[tt][ks] = *(const bf16x8*)(agg + base + ks*32 + quad*8);
                    }
                }
            }
        }
        // sibling mean -> LDS (a lane's 4 acc regs are one sibling group)
        #pragma unroll
        for (int tt = 0; tt < 2; ++tt){
            const int g = w*8 + tt*4 + quad;
            #pragma unroll
            for (int nt = 0; nt < 8; ++nt){
                int col = nt*16 + l15;
                float b = bs[col];
                float s = relu(acc[tt][nt][0]+b) + relu(acc[tt][nt][1]+b)
                        + relu(acc[tt][nt][2]+b) + relu(acc[tt][nt][3]+b);
                lds_sib[g*LPAD + col] = tobf(s * 0.25f);
            }
        }
        __syncthreads();
        // stage 2 (2 waves): parent agg
        if (w < 2){
            f32x4 a2c[8];
            #pragma unroll
            for (int i = 0; i < 8; ++i) a2c[i] = f32x4{0.f,0.f,0.f,0.f};
            bf16x8 a2[4];
            #pragma unroll
            for (int ks = 0; ks < 4; ++ks)
                a2[ks] = *(const bf16x8*)&lds_sib[(w*16 + l15)*LPAD + ks*32 + quad*8];
            #pragma unroll
            for (int ks = 0; ks < 4; ++ks){
                #pragma unroll
                for (int nt = 0; nt < 8; ++nt){
                    bf16x8 bfrag = *(const bf16x8*)&lds_wc[(nt*16 + l15)*LPAD + ks*32 + quad*8];
                    mfma_acc(a2c[nt], a2[ks], bfrag);
                }
            }
            #pragma unroll
            for (int nt = 0; nt < 8; ++nt){
                int col = nt*16 + l15;
                float b = bc[col];
                float r01 = 0.5f*(relu(a2c[nt][0]+b) + relu(a2c[nt][1]+b));
                float r23 = 0.5f*(relu(a2c[nt][2]+b) + relu(a2c[nt][3]+b));
                if (p0 < n_par)
                    agg[(parent_base + p0)*DIM + col] = tobf(pinit[0][nt] + r01);
                if (p0 + 1 < n_par)
                    agg[(parent_base + p0 + 1)*DIM + col] = tobf(pinit[1][nt] + r23);
            }
        }
        __syncthreads();        // protect lds_sib reuse
        tile = next;
    }
}

// ============================================================================
// down level (tile loop): ctx[child] = (ctxh[parent] + sum_sibs h - h_self)/4
// Wx in LDS once; double-buffered ctxh -> 1 barrier per tile.
// ============================================================================
__global__ __launch_bounds__(256, 3) void down_kernel(
    const __bf16* __restrict__ wts,     // Wx @32768
    const float* __restrict__ bx,
    const __bf16* __restrict__ agg,
    __bf16* __restrict__ ctx,
    long long parent_base, long long child_base, long long n_par)
{
    __shared__ __bf16 lds_w[128*LPAD];
    __shared__ float lds_ctxh[2][16*132];

    const int t = threadIdx.x;
    const int w = t >> 6, lane = t & 63, quad = lane >> 4, l15 = lane & 15;
    const long long n_child = n_par*8;
    const int ntiles = (int)((n_child + 127) >> 7);
    const int G = gridDim.x;

    load_w_lds(wts + 32768, lds_w, 128);
    __syncthreads();

    int buf = 0;
    for (int tile = blockIdx.x; tile < ntiles; tile += G, buf ^= 1){
        const long long rowbase = (long long)tile*128 + w*32;
        // loads: child agg frags (all), parent ctx frags (wave 0)
        bf16x8 a[2][4];
        #pragma unroll
        for (int tt = 0; tt < 2; ++tt){
            long long r = rowbase + tt*16 + l15;
            if (r >= n_child) r = n_child - 1;
            #pragma unroll
            for (int ks = 0; ks < 4; ++ks)
                a[tt][ks] = *(const bf16x8*)(agg + (child_base + r)*DIM + ks*32 + quad*8);
        }
        bf16x8 pc[4];
        if (w == 0){
            long long p = (long long)tile*16 + l15;
            if (p >= n_par) p = n_par - 1;
            #pragma unroll
            for (int ks = 0; ks < 4; ++ks)
                pc[ks] = *(const bf16x8*)(ctx + (parent_base + p)*DIM + ks*32 + quad*8);
        }
        // wave0: ctxh for the tile's 16 parents
        if (w == 0){
            f32x4 cacc[8];
            #pragma unroll
            for (int i = 0; i < 8; ++i) cacc[i] = f32x4{0.f,0.f,0.f,0.f};
            #pragma unroll
            for (int ks = 0; ks < 4; ++ks){
                #pragma unroll
                for (int nt = 0; nt < 8; ++nt){
                    bf16x8 bfrag = *(const bf16x8*)&lds_w[(nt*16 + l15)*LPAD + ks*32 + quad*8];
                    mfma_acc(cacc[nt], pc[ks], bfrag);
                }
            }
            #pragma unroll
            for (int nt = 0; nt < 8; ++nt){
                int col = nt*16 + l15;
                float b = bx[col];
                #pragma unroll
                for (int rg = 0; rg < 4; ++rg)
                    lds_ctxh[buf][(quad*4 + rg)*132 + col] = relu(cacc[nt][rg] + b);
            }
        }
        // all: h = relu(Wx.child_agg + bx)
        f32x4 acc[2][8];
        #pragma unroll
        for (int tt = 0; tt < 2; ++tt)
            #pragma unroll
            for (int i = 0; i < 8; ++i) acc[tt][i] = f32x4{0.f,0.f,0.f,0.f};
        #pragma unroll
        for (int ks = 0; ks < 4; ++ks){
            #pragma unroll
            for (int nt = 0; nt < 8; ++nt){
                bf16x8 bfrag = *(const bf16x8*)&lds_w[(nt*16 + l15)*LPAD + ks*32 + quad*8];
                mfma_acc(acc[0][nt], a[0][ks], bfrag);
                mfma_acc(acc[1][nt], a[1][ks], bfrag);
            }
        }
        __syncthreads();            // ctxh[buf] ready
        // epilogue: child ctx stores
        #pragma unroll
        for (int tt = 0; tt < 2; ++tt){
            const long long rb = rowbase + tt*16 + quad*4;
            const int p_loc = w*4 + tt*2 + (quad >> 1);
            #pragma unroll
            for (int nt = 0; nt < 8; ++nt){
                int col = nt*16 + l15;
                float b = bx[col];
                float h0 = relu(acc[tt][nt][0]+b), h1 = relu(acc[tt][nt][1]+b);
                float h2 = relu(acc[tt][nt][2]+b), h3 = relu(acc[tt][nt][3]+b);
                float s = h0 + h1 + h2 + h3;
                float ch = lds_ctxh[buf][p_loc*132 + col];
                if (rb   < n_child) ctx[(child_base + rb  )*DIM + col] = tobf((ch + s - h0)*0.25f);
                if (rb+1 < n_child) ctx[(child_base + rb+1)*DIM + col] = tobf((ch + s - h1)*0.25f);
                if (rb+2 < n_child) ctx[(child_base + rb+2)*DIM + col] = tobf((ch + s - h2)*0.25f);
                if (rb+3 < n_child) ctx[(child_base + rb+3)*DIM + col] = tobf((ch + s - h3)*0.25f);
            }
        }
    }
}

// ============================================================================
// final (tile loop, barrier-free steady state):
// out = relu([ctx,agg] @ Wf^T + bf) @ Wh^T + bh
// ============================================================================
__global__ __launch_bounds__(256, 2) void final_kernel(
    const __bf16* __restrict__ wts,     // Wf @49152, row stride 256
    const __bf16* __restrict__ ctx,
    const __bf16* __restrict__ agg,
    const float* __restrict__ bf_,
    const float* __restrict__ Wh, const float* __restrict__ bh,
    float* __restrict__ out)
{
    __shared__ __bf16 lds_w0[128*LPAD];
    __shared__ __bf16 lds_w1[128*LPAD];

    const int t = threadIdx.x;
    const int w = t >> 6, lane = t & 63, quad = lane >> 4, l15 = lane & 15;
    const int ntiles = (int)((NTOT + 127) >> 7);
    const int G = gridDim.x;

    load_w_lds(wts + 49152,       lds_w0, 256);   // Wf[:,0:128]   (ctx half)
    load_w_lds(wts + 49152 + 128, lds_w1, 256);   // Wf[:,128:256] (agg half)
    __syncthreads();

    for (int tile = blockIdx.x; tile < ntiles; tile += G){
        const long long rowbase = (long long)tile*128 + w*32;
        bf16x8 a0[2][4], a1[2][4];
        #pragma unroll
        for (int tt = 0; tt < 2; ++tt){
            long long r = rowbase + tt*16 + l15;
            if (r >= NTOT) r = NTOT - 1;
            #pragma unroll
            for (int ks = 0; ks < 4; ++ks){
                a0[tt][ks] = *(const bf16x8*)(ctx + r*DIM + ks*32 + quad*8);
                a1[tt][ks] = *(const bf16x8*)(agg + r*DIM + ks*32 + quad*8);
            }
        }
        f32x4 acc[2][8];
        #pragma unroll
        for (int tt = 0; tt < 2; ++tt)
            #pragma unroll
            for (int i = 0; i < 8; ++i) acc[tt][i] = f32x4{0.f,0.f,0.f,0.f};
        #pragma unroll
        for (int ks = 0; ks < 4; ++ks){
            #pragma unroll
            for (int nt = 0; nt < 8; ++nt){
                bf16x8 b0 = *(const bf16x8*)&lds_w0[(nt*16 + l15)*LPAD + ks*32 + quad*8];
                bf16x8 b1 = *(const bf16x8*)&lds_w1[(nt*16 + l15)*LPAD + ks*32 + quad*8];
                mfma_acc(acc[0][nt], a0[0][ks], b0);
                mfma_acc(acc[1][nt], a0[1][ks], b0);
                mfma_acc(acc[0][nt], a1[0][ks], b1);
                mfma_acc(acc[1][nt], a1[1][ks], b1);
            }
        }
        #pragma unroll
        for (int tt = 0; tt < 2; ++tt){
            float q0 = 0.f, q1 = 0.f, q2 = 0.f, q3 = 0.f;
            #pragma unroll
            for (int nt = 0; nt < 8; ++nt){
                int col = nt*16 + l15;
                float b = bf_[col], wh = Wh[col];
                q0 += relu(acc[tt][nt][0]+b)*wh;
                q1 += relu(acc[tt][nt][1]+b)*wh;
                q2 += relu(acc[tt][nt][2]+b)*wh;
                q3 += relu(acc[tt][nt][3]+b)*wh;
            }
            #pragma unroll
            for (int m = 1; m < 16; m <<= 1){
                q0 += __shfl_xor(q0, m);
                q1 += __shfl_xor(q1, m);
                q2 += __shfl_xor(q2, m);
                q3 += __shfl_xor(q3, m);
            }
            if (l15 == 0){
                float bb = bh[0];
                long long r = rowbase + tt*16 + quad*4;
                if (r   < NTOT) out[r  ] = q0 + bb;
                if (r+1 < NTOT) out[r+1] = q1 + bb;
                if (r+2 < NTOT) out[r+2] = q2 + bb;
                if (r+3 < NTOT) out[r+3] = q3 + bb;
            }
        }
    }
}

// ============================================================================
// tiny up: levels l=2,1,0 in ONE block (cross-level values carried in LDS)
// ============================================================================
__global__ __launch_bounds__(256) void up_tiny_kernel(
    const __bf16* __restrict__ wts,
    const float* __restrict__ init,
    const float* __restrict__ bs, const float* __restrict__ bc,
    __bf16* __restrict__ agg)
{
    __shared__ __bf16 lds_ws[128*LPAD];
    __shared__ __bf16 lds_wc[128*LPAD];
    __shared__ __bf16 lds_sib[32*LPAD];
    __shared__ __bf16 lds_agg[64*LPAD];

    const int t = threadIdx.x;
    const int w = t >> 6, lane = t & 63, quad = lane >> 4, l15 = lane & 15;

    load_w_lds(wts,         lds_ws, 128);
    load_w_lds(wts + 16384, lds_wc, 128);
    __syncthreads();

    const long long CB[3] = {73, 9, 1};
    const long long PB[3] = {9, 1, 0};
    const long long NP[3] = {64, 8, 1};

    for (int li = 0; li < 3; ++li){
        const long long child_base = CB[li], parent_base = PB[li], n_par = NP[li];
        const long long n_child = n_par*8;
        const int ntiles = (int)((n_child + 127) >> 7);
        for (int tile = 0; tile < ntiles; ++tile){
            bf16x8 af[2][4];
            #pragma unroll
            for (int tt = 0; tt < 2; ++tt){
                long long r = (long long)tile*128 + w*32 + tt*16 + l15;
                if (r >= n_child) r = n_child - 1;
                #pragma unroll
                for (int ks = 0; ks < 4; ++ks){
                    if (li == 0)
                        af[tt][ks] = *(const bf16x8*)(agg + (child_base + r)*DIM + ks*32 + quad*8);
                    else
                        af[tt][ks] = *(const bf16x8*)&lds_agg[r*LPAD + ks*32 + quad*8];
                }
            }
            float pinit[2][8];
            const long long p0 = (long long)tile*16 + w*8 + quad*2;
            if (w < 2){
                long long q0 = p0     < n_par ? p0     : n_par - 1;
                long long q1 = p0 + 1 < n_par ? p0 + 1 : n_par - 1;
                #pragma unroll
                for (int nt = 0; nt < 8; ++nt){
                    int col = nt*16 + l15;
                    pinit[0][nt] = init[(parent_base + q0)*DIM + col];
                    pinit[1][nt] = init[(parent_base + q1)*DIM + col];
                }
            }
            f32x4 acc[2][8];
            #pragma unroll
            for (int tt = 0; tt < 2; ++tt)
                #pragma unroll
                for (int i = 0; i < 8; ++i) acc[tt][i] = f32x4{0.f,0.f,0.f,0.f};
            #pragma unroll
            for (int ks = 0; ks < 4; ++ks){
                #pragma unroll
                for (int nt = 0; nt < 8; ++nt){
                    bf16x8 bfrag = *(const bf16x8*)&lds_ws[(nt*16 + l15)*LPAD + ks*32 + quad*8];
                    mfma_acc(acc[0][nt], af[0][ks], bfrag);
                    mfma_acc(acc[1][nt], af[1][ks], bfrag);
                }
            }
            #pragma unroll
            for (int tt = 0; tt < 2; ++tt){
                const int g = w*8 + tt*4 + quad;
                #pragma unroll
                for (int nt = 0; nt < 8; ++nt){
                    int col = nt*16 + l15;
                    float b = bs[col];
                    float s = relu(acc[tt][nt][0]+b) + relu(acc[tt][nt][1]+b)
                            + relu(acc[tt][nt][2]+b) + relu(acc[tt][nt][3]+b);
                    lds_sib[g*LPAD + col] = tobf(s * 0.25f);
                }
            }
            __syncthreads();
            if (w < 2){
                f32x4 a2c[8];
                #pragma unroll
                for (int i = 0; i < 8; ++i) a2c[i] = f32x4{0.f,0.f,0.f,0.f};
                bf16x8 a2[4];
                #pragma unroll
                for (int ks = 0; ks < 4; ++ks)
                    a2[ks] = *(const bf16x8*)&lds_sib[(w*16 + l15)*LPAD + ks*32 + quad*8];
                #pragma unroll
                for (int ks = 0; ks < 4; ++ks){
                    #pragma unroll
                    for (int nt = 0; nt < 8; ++nt){
                        bf16x8 bfrag = *(const bf16x8*)&lds_wc[(nt*16 + l15)*LPAD + ks*32 + quad*8];
                        mfma_acc(a2c[nt], a2[ks], bfrag);
                    }
                }
                #pragma unroll
                for (int nt = 0; nt < 8; ++nt){
                    int col = nt*16 + l15;
                    float b = bc[col];
                    float r01 = 0.5f*(relu(a2c[nt][0]+b) + relu(a2c[nt][1]+b));
                    float r23 = 0.5f*(relu(a2c[nt][2]+b) + relu(a2c[nt][3]+b));
                    if (p0 < n_par){
                        float vv = pinit[0][nt] + r01;
                        agg[(parent_base + p0)*DIM + col] = tobf(vv);
                        lds_agg[p0*LPAD + col] = tobf(vv);
                    }
                    if (p0 + 1 < n_par){
                        float vv = pinit[1][nt] + r23;
                        agg[(parent_base + p0 + 1)*DIM + col] = tobf(vv);
                        lds_agg[(p0 + 1)*LPAD + col] = tobf(vv);
                    }
                }
            }
            __syncthreads();
        }
    }
}

// ============================================================================
// tiny down: levels l=0,1,2 in ONE block (parent ctx carried in LDS)
// ============================================================================
__global__ __launch_bounds__(256) void down_tiny_kernel(
    const __bf16* __restrict__ wts,
    const float* __restrict__ bx,
    const __bf16* __restrict__ agg,
    __bf16* __restrict__ ctx)
{
    __shared__ __bf16 lds_w[128*LPAD];
    __shared__ float lds_ctxh[16*132];
    __shared__ __bf16 lds_ctx[64*LPAD];

    const int t = threadIdx.x;
    const int w = t >> 6, lane = t & 63, quad = lane >> 4, l15 = lane & 15;

    load_w_lds(wts + 32768, lds_w, 128);
    __syncthreads();

    const long long PBv[3] = {0, 1, 9};
    const long long CBv[3] = {1, 9, 73};
    const long long NPv[3] = {1, 8, 64};

    for (int li = 0; li < 3; ++li){
        const long long parent_base = PBv[li], child_base = CBv[li], n_par = NPv[li];
        const long long n_child = n_par*8;
        const int ntiles = (int)((n_child + 127) >> 7);
        for (int tile = 0; tile < ntiles; ++tile){
            const long long rowbase = (long long)tile*128 + w*32;
            bf16x8 a[2][4];
            #pragma unroll
            for (int tt = 0; tt < 2; ++tt){
                long long r = rowbase + tt*16 + l15;
                if (r >= n_child) r = n_child - 1;
                #pragma unroll
                for (int ks = 0; ks < 4; ++ks)
                    a[tt][ks] = *(const bf16x8*)(agg + (child_base + r)*DIM + ks*32 + quad*8);
            }
            if (w == 0){
                long long p = (long long)tile*16 + l15;
                if (p >= n_par) p = n_par - 1;
                bf16x8 pc[4];
                #pragma unroll
                for (int ks = 0; ks < 4; ++ks){
                    if (li == 0)
                        pc[ks] = *(const bf16x8*)(ctx + (parent_base + p)*DIM + ks*32 + quad*8);
                    else
                        pc[ks] = *(const bf16x8*)&lds_ctx[p*LPAD + ks*32 + quad*8];
                }
                f32x4 cacc[8];
                #pragma unroll
                for (int i = 0; i < 8; ++i) cacc[i] = f32x4{0.f,0.f,0.f,0.f};
                #pragma unroll
                for (int ks = 0; ks < 4; ++ks){
                    #pragma unroll
                    for (int nt = 0; nt < 8; ++nt){
                        bf16x8 bfrag = *(const bf16x8*)&lds_w[(nt*16 + l15)*LPAD + ks*32 + quad*8];
                        mfma_acc(cacc[nt], pc[ks], bfrag);
                    }
                }
                #pragma unroll
                for (int nt = 0; nt < 8; ++nt){
                    int col = nt*16 + l15;
                    float b = bx[col];
                    #pragma unroll
                    for (int rg = 0; rg < 4; ++rg)
                        lds_ctxh[(quad*4 + rg)*132 + col] = relu(cacc[nt][rg] + b);
                }
            }
            f32x4 acc[2][8];
            #pragma unroll
            for (int tt = 0; tt < 2; ++tt)
                #pragma unroll
                for (int i = 0; i < 8; ++i) acc[tt][i] = f32x4{0.f,0.f,0.f,0.f};
            #pragma unroll
            for (int ks = 0; ks < 4; ++ks){
                #pragma unroll
                for (int nt = 0; nt < 8; ++nt){
                    bf16x8 bfrag = *(const bf16x8*)&lds_w[(nt*16 + l15)*LPAD + ks*32 + quad*8];
                    mfma_acc(acc[0][nt], a[0][ks], bfrag);
                    mfma_acc(acc[1][nt], a[1][ks], bfrag);
                }
            }
            __syncthreads();
            #pragma unroll
            for (int tt = 0; tt < 2; ++tt){
                const long long rb = rowbase + tt*16 + quad*4;
                const int p_loc = w*4 + tt*2 + (quad >> 1);
                #pragma unroll
                for (int nt = 0; nt < 8; ++nt){
                    int col = nt*16 + l15;
                    float b = bx[col];
                    float h0 = relu(acc[tt][nt][0]+b), h1 = relu(acc[tt][nt][1]+b);
                    float h2 = relu(acc[tt][nt][2]+b), h3 = relu(acc[tt][nt][3]+b);
                    float s = h0 + h1 + h2 + h3;
                    float ch = lds_ctxh[p_loc*132 + col];
                    float c0 = (ch + s - h0)*0.25f, c1 = (ch + s - h1)*0.25f;
                    float c2 = (ch + s - h2)*0.25f, c3 = (ch + s - h3)*0.25f;
                    if (rb < n_child){
                        ctx[(child_base + rb)*DIM + col] = tobf(c0);
                        if (li < 2) lds_ctx[rb*LPAD + col] = tobf(c0);
                    }
                    if (rb+1 < n_child){
                        ctx[(child_base + rb+1)*DIM + col] = tobf(c1);
                        if (li < 2) lds_ctx[(rb+1)*LPAD + col] = tobf(c1);
                    }
                    if (rb+2 < n_child){
                        ctx[(child_base + rb+2)*DIM + col] = tobf(c2);
                        if (li < 2) lds_ctx[(rb+2)*LPAD + col] = tobf(c2);
                    }
                    if (rb+3 < n_child){
                        ctx[(child_base + rb+3)*DIM + col] = tobf(c3);
                        if (li < 2) lds_ctx[(rb+3)*LPAD + col] = tobf(c3);
                    }
                }
            }
            __syncthreads();
        }
    }
}

extern "C" void kernel_launch(void* const* d_in, const int* in_sizes, int n_in,
                              void* d_out, int out_size, void* d_ws, size_t ws_size,
                              hipStream_t stream)
{
    const float* init = (const float*)d_in[0];
    const float* Ws  = (const float*)d_in[1];
    const float* bs  = (const float*)d_in[2];
    const float* Wc  = (const float*)d_in[3];
    const float* bc  = (const float*)d_in[4];
    const float* Wx  = (const float*)d_in[5];
    const float* bx  = (const float*)d_in[6];
    const float* Wf  = (const float*)d_in[7];
    const float* bff = (const float*)d_in[8];
    const float* Wh  = (const float*)d_in[9];
    const float* bh  = (const float*)d_in[10];
    float* out = (float*)d_out;

    __bf16* agg = (__bf16*)d_ws;
    __bf16* ctx = agg + NTOT*DIM;
    __bf16* wts = ctx + NTOT*DIM;

    static const long long SZ[7] = {1,8,64,512,4096,32768,262144};
    static const long long OF[8] = {0,1,9,73,585,4681,37449,299593};

    prep_kernel<<<dim3(321), dim3(256), 0, stream>>>(Ws, Wc, Wx, Wf, wts, ctx);

    // ---- up sweep ----
    up_kernel<true ><<<dim3(512), dim3(256), 0, stream>>>(
        wts, init, bs, bc, agg, OF[6], OF[5], SZ[5]);          // 2048 tiles
    up_kernel<false><<<dim3(256), dim3(256), 0, stream>>>(
        wts, init, bs, bc, agg, OF[5], OF[4], SZ[4]);          // 256 tiles
    up_kernel<false><<<dim3(32),  dim3(256), 0, stream>>>(
        wts, init, bs, bc, agg, OF[4], OF[3], SZ[3]);          // 32 tiles
    up_tiny_kernel<<<dim3(1), dim3(256), 0, stream>>>(wts, init, bs, bc, agg);

    // ---- down sweep ----
    down_tiny_kernel<<<dim3(1), dim3(256), 0, stream>>>(wts, bx, agg, ctx);
    down_kernel<<<dim3(32),  dim3(256), 0, stream>>>(wts, bx, agg, ctx, OF[3], OF[4], SZ[3]);
    down_kernel<<<dim3(256), dim3(256), 0, stream>>>(wts, bx, agg, ctx, OF[4], OF[5], SZ[4]);
    down_kernel<<<dim3(768), dim3(256), 0, stream>>>(wts, bx, agg, ctx, OF[5], OF[6], SZ[5]);

    // ---- final (covers node 0 too) ----
    final_kernel<<<dim3(512), dim3(256), 0, stream>>>(wts, ctx, agg, bff, Wh, bh, out);
}